// Round 1
// baseline (448.991 us; speedup 1.0000x reference)
//
#include <hip/hip_runtime.h>
#include <hip/hip_bf16.h>

// Problem constants
// B=2, S=2048, D=1024, H=16, KVH=4, DK=64, R=16, groups=4, SCALING=1.0
// inputs (f32): query,key,value,(B,S,1024); Wq(1024,1024); Wk,Wv(1024,256); Wo(1024,1024)
//               Aq,Ak,Av,Ao(1024,16); Bq(16,1024); Bk,Bv(16,256); Bo(16,1024)
// out (f32): (B,S,1024)

typedef __attribute__((ext_vector_type(8))) short short8;
typedef __attribute__((ext_vector_type(4))) float f32x4;

#define DEV static __device__ __forceinline__

DEV unsigned short f32_to_bf16(float f) {
  unsigned int u = __float_as_uint(f);
  u += 0x7FFFu + ((u >> 16) & 1u);   // round-to-nearest-even
  return (unsigned short)(u >> 16);
}

DEV short8 cvt8(f32x4 a, f32x4 b) {
  short8 r;
  r[0] = (short)f32_to_bf16(a[0]);
  r[1] = (short)f32_to_bf16(a[1]);
  r[2] = (short)f32_to_bf16(a[2]);
  r[3] = (short)f32_to_bf16(a[3]);
  r[4] = (short)f32_to_bf16(b[0]);
  r[5] = (short)f32_to_bf16(b[1]);
  r[6] = (short)f32_to_bf16(b[2]);
  r[7] = (short)f32_to_bf16(b[3]);
  return r;
}

// ---------- cast f32 -> bf16 (vectorized, 8 elems/thread) ----------
__global__ __launch_bounds__(256) void cast_kernel(const float* __restrict__ in,
                                                   unsigned short* __restrict__ out,
                                                   int n8) {
  int i = blockIdx.x * 256 + threadIdx.x;
  if (i < n8) {
    f32x4 a = *(const f32x4*)(in + (size_t)i * 8);
    f32x4 b = *(const f32x4*)(in + (size_t)i * 8 + 4);
    *(short8*)(out + (size_t)i * 8) = cvt8(a, b);
  }
}

// ---------- W_eff^T: WT[n][k] = W[k][n] + sum_r A[k][r]*B[r][n], bf16 ----------
// grid (N/16, 64), block (16,16). K fixed = 1024. R fixed = 16.
__global__ __launch_bounds__(256) void weff_kernel(const float* __restrict__ W,
                                                   const float* __restrict__ A,
                                                   const float* __restrict__ Bm,
                                                   unsigned short* __restrict__ WT,
                                                   int N) {
  __shared__ float tile[16][17];
  const int tx = threadIdx.x, ty = threadIdx.y;
  const int n0 = blockIdx.x * 16, k0 = blockIdx.y * 16;
  const int n = n0 + tx, k = k0 + ty;
  float acc = W[(size_t)k * N + n];
#pragma unroll
  for (int r = 0; r < 16; ++r) acc += A[k * 16 + r] * Bm[(size_t)r * N + n];
  tile[ty][tx] = acc;
  __syncthreads();
  WT[(size_t)(n0 + ty) * 1024 + (k0 + tx)] = f32_to_bf16(tile[tx][ty]);
}

// ---------- bf16 MFMA GEMM: C(M=4096 x N) = X(4096x1024) * WT^T ----------
// WT is [N][1024] bf16 (pre-transposed). Block = 4 waves, tile 64(M) x 64(N).
// wave w: cols n0+w*16, 4 M-subtiles of 16. mfma_f32_16x16x32_bf16:
//   A frag: lane holds A[l&15][(l>>4)*8 + j]  (row-contig 16B load)
//   B frag: lane holds B[(l>>4)*8 + j][l&15] = WT[n=l&15][k-chunk] (row-contig)
//   C/D  : D[(l>>4)*4 + i][l&15]
// OUTMODE: 0 = bf16 row-major [M][N]; 1 = f32 row-major; 2 = bf16 V-transpose
//   (Vt[b][n][s] with b=row>>11, s=row&2047, layout [2*256][2048])
template <int OUTMODE>
__global__ __launch_bounds__(256) void gemm_kernel(const unsigned short* __restrict__ X,
                                                   const unsigned short* __restrict__ WT,
                                                   void* __restrict__ Cv, int N) {
  constexpr int K = 1024;
  const int w = threadIdx.x >> 6, l = threadIdx.x & 63;
  const int lr = l & 15, lg = l >> 4;
  const int m0 = blockIdx.y * 64;
  const int n0 = blockIdx.x * 64 + w * 16;
  const unsigned short* wrow = WT + (size_t)(n0 + lr) * K + lg * 8;
  const unsigned short* xrow = X + (size_t)(m0 + lr) * K + lg * 8;
  f32x4 acc[4];
#pragma unroll
  for (int mm = 0; mm < 4; ++mm) acc[mm] = f32x4{0.f, 0.f, 0.f, 0.f};

  for (int k0 = 0; k0 < K; k0 += 32) {
    short8 bfrag = *(const short8*)(wrow + k0);
#pragma unroll
    for (int mm = 0; mm < 4; ++mm) {
      short8 afrag = *(const short8*)(xrow + (size_t)mm * 16 * K + k0);
      acc[mm] = __builtin_amdgcn_mfma_f32_16x16x32_bf16(afrag, bfrag, acc[mm], 0, 0, 0);
    }
  }

#pragma unroll
  for (int mm = 0; mm < 4; ++mm) {
#pragma unroll
    for (int i = 0; i < 4; ++i) {
      const int row = m0 + mm * 16 + lg * 4 + i;
      const int col = n0 + lr;
      const float v = acc[mm][i];
      if (OUTMODE == 0) {
        ((unsigned short*)Cv)[(size_t)row * N + col] = f32_to_bf16(v);
      } else if (OUTMODE == 1) {
        ((float*)Cv)[(size_t)row * N + col] = v;
      } else {
        const int b = row >> 11, s = row & 2047;
        ((unsigned short*)Cv)[((size_t)(b * 256 + col)) * 2048 + s] = f32_to_bf16(v);
      }
    }
  }
}

// ---------- flash attention: causal + ALiBi + GQA ----------
// Q [B][S][1024] bf16 (head h at col h*64), K [B][S][256] bf16 (kv head at kv*64),
// Vt [(b*4+kv)*64 + d][s] bf16, out Xo [B][S][1024] bf16.
// grid (S/64, H, B), block 256 (4 waves). Wave w owns q rows [qt*64+w*16, +16).
__global__ __launch_bounds__(256) void attn_kernel(const unsigned short* __restrict__ Q,
                                                   const unsigned short* __restrict__ Kp,
                                                   const unsigned short* __restrict__ Vt,
                                                   unsigned short* __restrict__ Xo) {
  constexpr int S = 2048;
  const int w = threadIdx.x >> 6, l = threadIdx.x & 63;
  const int lr = l & 15, lg = l >> 4;
  const int qt = blockIdx.x, h = blockIdx.y, b = blockIdx.z;
  const int kv = h >> 2;
  const float slope = exp2f(-(float)(h + 1));
  const int q0 = qt * 64 + w * 16;

  // Q fragments (held for the whole k-loop): d-chunks 0..31 and 32..63
  const unsigned short* qp = Q + ((size_t)(b * S + q0 + lr)) * 1024 + h * 64 + lg * 8;
  const short8 aQ0 = *(const short8*)qp;
  const short8 aQ1 = *(const short8*)(qp + 32);

  const unsigned short* Kbase = Kp + (size_t)b * S * 256 + kv * 64 + lg * 8;
  const unsigned short* Vbase = Vt + ((size_t)(b * 4 + kv) * 64 + lr) * 2048 + lg * 8;

  __shared__ unsigned short plds[4][16][40];  // per-wave P tile, 80B row stride (16B-aligned)

  f32x4 o[4];
#pragma unroll
  for (int dt = 0; dt < 4; ++dt) o[dt] = f32x4{0.f, 0.f, 0.f, 0.f};
  float mrow[4] = {-3e38f, -3e38f, -3e38f, -3e38f};
  float lrow[4] = {0.f, 0.f, 0.f, 0.f};

  const int myq = q0 + lg * 4;            // this lane's 4 q-rows: myq+i
  const int nkt = (q0 + 15) / 32 + 1;     // causal k-tile count

  for (int kt = 0; kt < nkt; ++kt) {
    const int k0 = kt * 32;
    // K fragments: rows k0+lr (and +16), d-chunks per lg
    const unsigned short* kp0 = Kbase + (size_t)(k0 + lr) * 256;
    const short8 b00 = *(const short8*)kp0;
    const short8 b01 = *(const short8*)(kp0 + 32);
    const short8 b10 = *(const short8*)(kp0 + 16 * 256);
    const short8 b11 = *(const short8*)(kp0 + 16 * 256 + 32);

    f32x4 s0 = f32x4{0.f, 0.f, 0.f, 0.f};
    f32x4 s1 = f32x4{0.f, 0.f, 0.f, 0.f};
    s0 = __builtin_amdgcn_mfma_f32_16x16x32_bf16(aQ0, b00, s0, 0, 0, 0);
    s0 = __builtin_amdgcn_mfma_f32_16x16x32_bf16(aQ1, b01, s0, 0, 0, 0);
    s1 = __builtin_amdgcn_mfma_f32_16x16x32_bf16(aQ0, b10, s1, 0, 0, 0);
    s1 = __builtin_amdgcn_mfma_f32_16x16x32_bf16(aQ1, b11, s1, 0, 0, 0);

    const int c0 = k0 + lr, c1 = c0 + 16;
    float p0[4], p1[4];
#pragma unroll
    for (int i = 0; i < 4; ++i) {
      const int qq = myq + i;
      float v0 = (c0 <= qq) ? s0[i] * 0.125f + slope * (float)(c0 - qq) : -3e38f;
      float v1 = (c1 <= qq) ? s1[i] * 0.125f + slope * (float)(c1 - qq) : -3e38f;
      float t = fmaxf(v0, v1);
      t = fmaxf(t, __shfl_xor(t, 1));
      t = fmaxf(t, __shfl_xor(t, 2));
      t = fmaxf(t, __shfl_xor(t, 4));
      t = fmaxf(t, __shfl_xor(t, 8));
      const float mnew = fmaxf(mrow[i], t);
      const float f = __expf(mrow[i] - mnew);
      p0[i] = __expf(v0 - mnew);
      p1[i] = __expf(v1 - mnew);
      float rs = p0[i] + p1[i];
      rs += __shfl_xor(rs, 1);
      rs += __shfl_xor(rs, 2);
      rs += __shfl_xor(rs, 4);
      rs += __shfl_xor(rs, 8);
      lrow[i] = lrow[i] * f + rs;
      mrow[i] = mnew;
      o[0][i] *= f; o[1][i] *= f; o[2][i] *= f; o[3][i] *= f;
    }

    // P (acc layout) -> LDS -> A-fragment layout
#pragma unroll
    for (int i = 0; i < 4; ++i) {
      plds[w][lg * 4 + i][lr] = f32_to_bf16(p0[i]);
      plds[w][lg * 4 + i][lr + 16] = f32_to_bf16(p1[i]);
    }
    asm volatile("s_waitcnt lgkmcnt(0)" ::: "memory");
    const short8 pa = *(const short8*)(&plds[w][lr][lg * 8]);

#pragma unroll
    for (int dt = 0; dt < 4; ++dt) {
      const short8 bV = *(const short8*)(Vbase + (size_t)dt * 16 * 2048 + k0);
      o[dt] = __builtin_amdgcn_mfma_f32_16x16x32_bf16(pa, bV, o[dt], 0, 0, 0);
    }
  }

  unsigned short* op = Xo + ((size_t)(b * S + myq)) * 1024 + h * 64 + lr;
#pragma unroll
  for (int dt = 0; dt < 4; ++dt) {
#pragma unroll
    for (int i = 0; i < 4; ++i) {
      op[(size_t)i * 1024 + dt * 16] = f32_to_bf16(o[dt][i] / lrow[i]);
    }
  }
}

extern "C" void kernel_launch(void* const* d_in, const int* in_sizes, int n_in,
                              void* d_out, int out_size, void* d_ws, size_t ws_size,
                              hipStream_t stream) {
  const float* query = (const float*)d_in[0];
  const float* key   = (const float*)d_in[1];
  const float* value = (const float*)d_in[2];
  const float* Wq = (const float*)d_in[3];
  const float* Wk = (const float*)d_in[4];
  const float* Wv = (const float*)d_in[5];
  const float* Wo = (const float*)d_in[6];
  const float* Aq = (const float*)d_in[7];
  const float* Bq = (const float*)d_in[8];
  const float* Ak = (const float*)d_in[9];
  const float* Bk = (const float*)d_in[10];
  const float* Av = (const float*)d_in[11];
  const float* Bv = (const float*)d_in[12];
  const float* Ao = (const float*)d_in[13];
  const float* Bo = (const float*)d_in[14];

  // workspace layout (all bf16/ushort), total 33 MB
  unsigned short* ws  = (unsigned short*)d_ws;
  unsigned short* WqT = ws;                       // 1024*1024
  unsigned short* WkT = WqT + 1024 * 1024;        // 256*1024
  unsigned short* WvT = WkT + 256 * 1024;         // 256*1024
  unsigned short* WoT = WvT + 256 * 1024;         // 1024*1024
  unsigned short* Qw  = WoT + 1024 * 1024;        // 4096*1024
  unsigned short* Kw  = Qw + 4096 * 1024;         // 4096*256
  unsigned short* Vtw = Kw + 4096 * 256;          // [2*4*64][2048] = 4096*256
  unsigned short* Xw  = Vtw + 4096 * 256;         // 4096*1024 (attn out)
  unsigned short* Xc  = Xw + 4096 * 1024;         // 4096*1024 (bf16 input cast, reused 3x)

  const dim3 b16(16, 16);
  weff_kernel<<<dim3(64, 64), b16, 0, stream>>>(Wq, Aq, Bq, WqT, 1024);
  weff_kernel<<<dim3(16, 64), b16, 0, stream>>>(Wk, Ak, Bk, WkT, 256);
  weff_kernel<<<dim3(16, 64), b16, 0, stream>>>(Wv, Av, Bv, WvT, 256);
  weff_kernel<<<dim3(64, 64), b16, 0, stream>>>(Wo, Ao, Bo, WoT, 1024);

  const int n8 = 4096 * 1024 / 8;

  cast_kernel<<<2048, 256, 0, stream>>>(query, Xc, n8);
  gemm_kernel<0><<<dim3(16, 64), 256, 0, stream>>>(Xc, WqT, Qw, 1024);

  cast_kernel<<<2048, 256, 0, stream>>>(key, Xc, n8);
  gemm_kernel<0><<<dim3(4, 64), 256, 0, stream>>>(Xc, WkT, Kw, 256);

  cast_kernel<<<2048, 256, 0, stream>>>(value, Xc, n8);
  gemm_kernel<2><<<dim3(4, 64), 256, 0, stream>>>(Xc, WvT, Vtw, 256);

  attn_kernel<<<dim3(32, 16, 2), 256, 0, stream>>>(Qw, Kw, Vtw, Xw);

  gemm_kernel<1><<<dim3(16, 64), 256, 0, stream>>>(Xw, WoT, (float*)d_out, 1024);
}

// Round 2
// 278.731 us; speedup vs baseline: 1.6108x; 1.6108x over previous
//
#include <hip/hip_runtime.h>
#include <hip/hip_bf16.h>

// B=2, S=2048, D=1024, H=16, KVH=4, DK=64, R=16, groups=4, SCALING=1.0
// out (f32): (B,S,1024)

typedef __attribute__((ext_vector_type(8))) short short8;
typedef __attribute__((ext_vector_type(4))) float f32x4;
typedef __attribute__((ext_vector_type(16))) float f32x16;
typedef __attribute__((ext_vector_type(2))) unsigned int uint2v;
typedef __attribute__((ext_vector_type(4))) unsigned short ushort4v;

#define DEV static __device__ __forceinline__

DEV unsigned short f32_to_bf16(float f) {
  unsigned int u = __float_as_uint(f);
  u += 0x7FFFu + ((u >> 16) & 1u);   // RNE
  return (unsigned short)(u >> 16);
}

DEV unsigned int cvt_pk_bf16(float lo, float hi) {
  unsigned int r;
  asm("v_cvt_pk_bf16_f32 %0, %1, %2" : "=v"(r) : "v"(lo), "v"(hi));
  return r;
}

DEV short8 cvt8(f32x4 a, f32x4 b) {
  short8 r;
  r[0] = (short)f32_to_bf16(a[0]); r[1] = (short)f32_to_bf16(a[1]);
  r[2] = (short)f32_to_bf16(a[2]); r[3] = (short)f32_to_bf16(a[3]);
  r[4] = (short)f32_to_bf16(b[0]); r[5] = (short)f32_to_bf16(b[1]);
  r[6] = (short)f32_to_bf16(b[2]); r[7] = (short)f32_to_bf16(b[3]);
  return r;
}

// ---------- cast f32 -> bf16 ----------
__global__ __launch_bounds__(256) void cast_kernel(const float* __restrict__ in,
                                                   unsigned short* __restrict__ out,
                                                   int n8) {
  int i = blockIdx.x * 256 + threadIdx.x;
  if (i < n8) {
    f32x4 a = *(const f32x4*)(in + (size_t)i * 8);
    f32x4 b = *(const f32x4*)(in + (size_t)i * 8 + 4);
    *(short8*)(out + (size_t)i * 8) = cvt8(a, b);
  }
}

// ---------- all four W_eff^T in one launch ----------
// WT[n][k] = W[k][n] + sum_r A[k][r]*B[r][n], bf16.  grid(160,64) block(16,16)
__global__ __launch_bounds__(256) void weff_all_kernel(
    const float* __restrict__ Wq, const float* __restrict__ Aq, const float* __restrict__ Bq, unsigned short* __restrict__ WqT,
    const float* __restrict__ Wk, const float* __restrict__ Ak, const float* __restrict__ Bk, unsigned short* __restrict__ WkT,
    const float* __restrict__ Wv, const float* __restrict__ Av, const float* __restrict__ Bv, unsigned short* __restrict__ WvT,
    const float* __restrict__ Wo, const float* __restrict__ Ao, const float* __restrict__ Bo, unsigned short* __restrict__ WoT) {
  __shared__ float tile[16][17];
  const int bx = blockIdx.x;
  const float *W, *A, *Bm; unsigned short* WT; int N, nb;
  if (bx < 64)       { W = Wq; A = Aq; Bm = Bq; WT = WqT; N = 1024; nb = bx; }
  else if (bx < 80)  { W = Wk; A = Ak; Bm = Bk; WT = WkT; N = 256;  nb = bx - 64; }
  else if (bx < 96)  { W = Wv; A = Av; Bm = Bv; WT = WvT; N = 256;  nb = bx - 80; }
  else               { W = Wo; A = Ao; Bm = Bo; WT = WoT; N = 1024; nb = bx - 96; }
  const int tx = threadIdx.x, ty = threadIdx.y;
  const int n0 = nb * 16, k0 = blockIdx.y * 16;
  const int n = n0 + tx, k = k0 + ty;
  float acc = W[(size_t)k * N + n];
#pragma unroll
  for (int r = 0; r < 16; ++r) acc += A[k * 16 + r] * Bm[(size_t)r * N + n];
  tile[ty][tx] = acc;
  __syncthreads();
  WT[(size_t)(n0 + ty) * 1024 + (k0 + tx)] = f32_to_bf16(tile[tx][ty]);
}

// ---------- bf16 MFMA GEMM: C(4096 x N) = X(4096x1024) * WT^T ----------
// Block 4 waves (2x2), tile 128x128; wave computes 64x64 (4x4 frags of 16x16x32).
// OUTMODE: 0 bf16 row-major; 1 f32 row-major; 2 Vt [(b*4+kv)*64+d][2048];
//          3 K head-major [(b*4+kv)*2048+s][64]
template <int OUTMODE>
__global__ __launch_bounds__(256) void gemm2_kernel(const unsigned short* __restrict__ X,
                                                    const unsigned short* __restrict__ WT,
                                                    void* __restrict__ Cv, int N) {
  constexpr int K = 1024;
  const int w = threadIdx.x >> 6, l = threadIdx.x & 63;
  const int lr = l & 15, lg = l >> 4;
  const int wm = w >> 1, wn = w & 1;
  const int m0 = blockIdx.y * 128 + wm * 64;
  const int n0 = blockIdx.x * 128 + wn * 64;
  const unsigned short* xrow = X + (size_t)(m0 + lr) * K + lg * 8;
  const unsigned short* wrow = WT + (size_t)(n0 + lr) * K + lg * 8;
  f32x4 acc[4][4];
#pragma unroll
  for (int mm = 0; mm < 4; ++mm)
#pragma unroll
    for (int nn = 0; nn < 4; ++nn) acc[mm][nn] = f32x4{0.f, 0.f, 0.f, 0.f};

  short8 a[4], bf[4];
#pragma unroll
  for (int mm = 0; mm < 4; ++mm) a[mm] = *(const short8*)(xrow + (size_t)mm * 16 * K);
#pragma unroll
  for (int nn = 0; nn < 4; ++nn) bf[nn] = *(const short8*)(wrow + (size_t)nn * 16 * K);

  for (int k0 = 0; k0 < K; k0 += 32) {
    short8 an[4], bn[4];
    const bool more = (k0 + 32 < K);
    if (more) {
#pragma unroll
      for (int mm = 0; mm < 4; ++mm) an[mm] = *(const short8*)(xrow + (size_t)mm * 16 * K + k0 + 32);
#pragma unroll
      for (int nn = 0; nn < 4; ++nn) bn[nn] = *(const short8*)(wrow + (size_t)nn * 16 * K + k0 + 32);
    }
#pragma unroll
    for (int mm = 0; mm < 4; ++mm)
#pragma unroll
      for (int nn = 0; nn < 4; ++nn)
        acc[mm][nn] = __builtin_amdgcn_mfma_f32_16x16x32_bf16(a[mm], bf[nn], acc[mm][nn], 0, 0, 0);
    if (more) {
#pragma unroll
      for (int mm = 0; mm < 4; ++mm) { a[mm] = an[mm]; bf[mm] = bn[mm]; }
    }
  }

#pragma unroll
  for (int mm = 0; mm < 4; ++mm)
#pragma unroll
    for (int nn = 0; nn < 4; ++nn)
#pragma unroll
      for (int i = 0; i < 4; ++i) {
        const int row = m0 + mm * 16 + lg * 4 + i;
        const int col = n0 + nn * 16 + lr;
        const float v = acc[mm][nn][i];
        if (OUTMODE == 0) {
          ((unsigned short*)Cv)[(size_t)row * N + col] = f32_to_bf16(v);
        } else if (OUTMODE == 1) {
          ((float*)Cv)[(size_t)row * N + col] = v;
        } else if (OUTMODE == 2) {
          ((unsigned short*)Cv)[((size_t)((row >> 11) * 4 + (col >> 6)) * 64 + (col & 63)) * 2048 + (row & 2047)] = f32_to_bf16(v);
        } else {
          ((unsigned short*)Cv)[((size_t)((row >> 11) * 4 + (col >> 6)) * 2048 + (row & 2047)) * 64 + (col & 63)] = f32_to_bf16(v);
        }
      }
}

// ---------- flash attention, swapped-QK 32x32 structure ----------
// Q [B][S][1024] bf16; Kh [(b*4+kv)*2048+s][64] bf16; Vt [(b*4+kv)*64+d][2048] bf16
// grid (16, 16, 2) block 256 (4 waves); wave w owns q rows qt*128+w*32 .. +31.
// Swapped QK^T: sacc[r] = S[k = k0+(r&3)+8*(r>>2)+4*hi][q = lane&31]; softmax lane-local.
__global__ __launch_bounds__(256) void attn2_kernel(const unsigned short* __restrict__ Q,
                                                    const unsigned short* __restrict__ Kh,
                                                    const unsigned short* __restrict__ Vt,
                                                    unsigned short* __restrict__ Xo) {
  const int l = threadIdx.x & 63, w = threadIdx.x >> 6;
  const int cq = l & 31, hi = l >> 5;
  const int qt = (int)(gridDim.x - 1 - blockIdx.x);   // longest-first
  const int h = blockIdx.y, b = blockIdx.z;
  const int kv = h >> 2;
  const int q0 = qt * 128 + w * 32;
  const int q = q0 + cq;
  const float LOG2E = 1.44269504f;
  const float slope2 = exp2f(-(float)(h + 1)) * LOG2E;   // ALiBi slope in log2 domain
  const float qscale = 0.125f * LOG2E;

  const unsigned short* qp = Q + ((size_t)(b * 2048 + q)) * 1024 + h * 64 + hi * 8;
  short8 qf[4];
#pragma unroll
  for (int c = 0; c < 4; ++c) qf[c] = *(const short8*)(qp + c * 16);

  const unsigned short* Kb = Kh + ((size_t)(b * 4 + kv) * 2048) * 64 + hi * 8;
  const unsigned short* Vb = Vt + ((size_t)(b * 4 + kv) * 64 + cq) * 2048 + hi * 8;

  f32x16 oA, oB;
#pragma unroll
  for (int r = 0; r < 16; ++r) { oA[r] = 0.f; oB[r] = 0.f; }
  float mrun = -3e38f, lrun = 0.f;

  const float fhi = 4.0f * (float)hi;
  const int nkt = (q0 + 31) / 64 + 1;

  for (int kt = 0; kt < nkt; ++kt) {
    const int k0 = kt * 64;
    const unsigned short* kp = Kb + (size_t)(k0 + cq) * 64;

    f32x16 sA, sB;
#pragma unroll
    for (int r = 0; r < 16; ++r) { sA[r] = 0.f; sB[r] = 0.f; }
#pragma unroll
    for (int c = 0; c < 4; ++c) {
      short8 kfa = *(const short8*)(kp + c * 16);
      short8 kfb = *(const short8*)(kp + 32 * 64 + c * 16);
      sA = __builtin_amdgcn_mfma_f32_32x32x16_bf16(kfa, qf[c], sA, 0, 0, 0);
      sB = __builtin_amdgcn_mfma_f32_32x32x16_bf16(kfb, qf[c], sB, 0, 0, 0);
    }

    // scale + ALiBi (+ causal mask on diagonal tile only)
    const float fhb   = fmaf(slope2, fhi, slope2 * (float)(k0 - q));
    const float fhb32 = fmaf(slope2, fhi, slope2 * (float)(k0 + 32 - q));
    const bool masked = (kt == nkt - 1);
    const int ikq4 = k0 - q + 4 * hi;
    float svA[16], svB[16];
#pragma unroll
    for (int r = 0; r < 16; ++r) {
      const int koffc = (r & 3) + 8 * (r >> 2);
      const float kf = (float)koffc;
      float va = fmaf(sA[r], qscale, fmaf(slope2, kf, fhb));
      float vb = fmaf(sB[r], qscale, fmaf(slope2, kf, fhb32));
      if (masked) {
        if (ikq4 + koffc > 0) va = -3e38f;
        if (ikq4 + koffc + 32 > 0) vb = -3e38f;
      }
      svA[r] = va; svB[r] = vb;
    }

    // lane-local max, one cross-half shuffle
    float mx = svA[0];
#pragma unroll
    for (int r = 1; r < 16; ++r) mx = fmaxf(mx, svA[r]);
#pragma unroll
    for (int r = 0; r < 16; ++r) mx = fmaxf(mx, svB[r]);
    mx = fmaxf(mx, __shfl_xor(mx, 32));
    const float mnew = fmaxf(mrun, mx);
    const float fsc = exp2f(mrun - mnew);
    mrun = mnew;

    float pA[16], pB[16];
    float ls = 0.f;
#pragma unroll
    for (int r = 0; r < 16; ++r) {
      pA[r] = exp2f(svA[r] - mnew);
      pB[r] = exp2f(svB[r] - mnew);
      ls += pA[r] + pB[r];
    }
    ls += __shfl_xor(ls, 32);
    lrun = fmaf(lrun, fsc, ls);
#pragma unroll
    for (int r = 0; r < 16; ++r) { oA[r] *= fsc; oB[r] *= fsc; }

    // P -> bf16 B-fragments (cvt_pk + permlane32_swap), then PV
#define PV_HALF(PARR, KBASE)                                                          \
    {                                                                                 \
      _Pragma("unroll")                                                               \
      for (int g = 0; g < 2; ++g) {                                                   \
        unsigned int a0 = cvt_pk_bf16(PARR[g * 8 + 0], PARR[g * 8 + 1]);              \
        unsigned int b0 = cvt_pk_bf16(PARR[g * 8 + 4], PARR[g * 8 + 5]);              \
        unsigned int a1 = cvt_pk_bf16(PARR[g * 8 + 2], PARR[g * 8 + 3]);              \
        unsigned int b1 = cvt_pk_bf16(PARR[g * 8 + 6], PARR[g * 8 + 7]);              \
        uint2v r0 = __builtin_amdgcn_permlane32_swap(a0, b0, false, false);           \
        uint2v r1 = __builtin_amdgcn_permlane32_swap(a1, b1, false, false);           \
        union { unsigned int u[4]; short8 s; } pb_;                                   \
        pb_.u[0] = r0[0]; pb_.u[1] = r1[0]; pb_.u[2] = r0[1]; pb_.u[3] = r1[1];       \
        const unsigned short* vp = Vb + (KBASE) + g * 16;                             \
        short8 v0 = *(const short8*)(vp);                                             \
        short8 v1 = *(const short8*)(vp + (size_t)32 * 2048);                         \
        oA = __builtin_amdgcn_mfma_f32_32x32x16_bf16(v0, pb_.s, oA, 0, 0, 0);         \
        oB = __builtin_amdgcn_mfma_f32_32x32x16_bf16(v1, pb_.s, oB, 0, 0, 0);         \
      }                                                                               \
    }
    PV_HALF(pA, k0)
    PV_HALF(pB, k0 + 32)
#undef PV_HALF
  }

  const float rinv = __builtin_amdgcn_rcpf(lrun);
  unsigned short* op = Xo + ((size_t)(b * 2048 + q)) * 1024 + h * 64 + hi * 4;
#pragma unroll
  for (int rg = 0; rg < 4; ++rg) {
    ushort4v t0, t1;
#pragma unroll
    for (int i = 0; i < 4; ++i) {
      t0[i] = f32_to_bf16(oA[rg * 4 + i] * rinv);
      t1[i] = f32_to_bf16(oB[rg * 4 + i] * rinv);
    }
    *(ushort4v*)(op + rg * 8) = t0;
    *(ushort4v*)(op + 32 + rg * 8) = t1;
  }
}

extern "C" void kernel_launch(void* const* d_in, const int* in_sizes, int n_in,
                              void* d_out, int out_size, void* d_ws, size_t ws_size,
                              hipStream_t stream) {
  const float* query = (const float*)d_in[0];
  const float* key   = (const float*)d_in[1];
  const float* value = (const float*)d_in[2];
  const float* Wq = (const float*)d_in[3];
  const float* Wk = (const float*)d_in[4];
  const float* Wv = (const float*)d_in[5];
  const float* Wo = (const float*)d_in[6];
  const float* Aq = (const float*)d_in[7];
  const float* Bq = (const float*)d_in[8];
  const float* Ak = (const float*)d_in[9];
  const float* Bk = (const float*)d_in[10];
  const float* Av = (const float*)d_in[11];
  const float* Bv = (const float*)d_in[12];
  const float* Ao = (const float*)d_in[13];
  const float* Bo = (const float*)d_in[14];

  unsigned short* ws  = (unsigned short*)d_ws;
  unsigned short* WqT = ws;                       // 1M
  unsigned short* WkT = WqT + 1024 * 1024;        // 256K
  unsigned short* WvT = WkT + 256 * 1024;         // 256K
  unsigned short* WoT = WvT + 256 * 1024;         // 1M
  unsigned short* Qw  = WoT + 1024 * 1024;        // 4M   [B][S][1024]
  unsigned short* Khm = Qw + 4096 * 1024;         // 1M   [(b*4+kv)*2048+s][64]
  unsigned short* Vtw = Khm + 4096 * 256;         // 1M   [(b*4+kv)*64+d][2048]
  unsigned short* Xw  = Vtw + 4096 * 256;         // 4M   attn out [B][S][1024]
  unsigned short* Xc  = Xw + 4096 * 1024;         // 4M   bf16 cast buffer

  weff_all_kernel<<<dim3(160, 64), dim3(16, 16), 0, stream>>>(
      Wq, Aq, Bq, WqT, Wk, Ak, Bk, WkT, Wv, Av, Bv, WvT, Wo, Ao, Bo, WoT);

  const int n8 = 4096 * 1024 / 8;

  cast_kernel<<<2048, 256, 0, stream>>>(query, Xc, n8);
  gemm2_kernel<0><<<dim3(8, 32), 256, 0, stream>>>(Xc, WqT, Qw, 1024);

  cast_kernel<<<2048, 256, 0, stream>>>(key, Xc, n8);
  gemm2_kernel<3><<<dim3(2, 32), 256, 0, stream>>>(Xc, WkT, Khm, 256);

  cast_kernel<<<2048, 256, 0, stream>>>(value, Xc, n8);
  gemm2_kernel<2><<<dim3(2, 32), 256, 0, stream>>>(Xc, WvT, Vtw, 256);

  attn2_kernel<<<dim3(16, 16, 2), 256, 0, stream>>>(Qw, Khm, Vtw, Xw);

  gemm2_kernel<1><<<dim3(8, 32), 256, 0, stream>>>(Xw, WoT, (float*)d_out, 1024);
}